// Round 2
// baseline (2608.896 us; speedup 1.0000x reference)
//
#include <hip/hip_runtime.h>
#include <cstdint>
#include <cstddef>

#define S 108
#define NEMIT 126
#define NCOD 16
#define T_LEN 2048
#define N_BATCH 256
#define MAXP 20   // max in-degree of column pair (2l,2l+1) is 19 (cols 52+53)

// ---- emission-structure enumeration (mirrors _emission_structure) ----
// sym codes: 0..3 = A,C,G,T ; 4 = 'N' (expands to {0,1,2,3}) ; 5 = 'X' marker
__device__ __forceinline__ int maskFor(int sym, int add4) {
  int m = (sym == 4) ? 0xF : (1 << sym);
  if (add4) m |= 0x10;           // literal kmer digit 4 ("pad") allowed
  return m;
}

// Iterates accepted kmer ids in EXACT Python product() order.
template <typename F>
__device__ __forceinline__ void enumCall(int s0, int s1, int s2, int xmust, F&& f) {
  int m0 = maskFor(s0, xmust < 2 ? 1 : 0);
  int m1 = maskFor(s1, xmust < 1 ? 1 : 0);
  int m2 = maskFor(s2, 0);
  for (int x0 = 0; x0 < 5; x0++) {
    if (!((m0 >> x0) & 1)) continue;
    for (int x1 = 0; x1 < 5; x1++) {
      if (!((m1 >> x1) & 1)) continue;
      if (x0 != 4 && x1 == 4) continue;   // 4s must be a prefix among first two
      for (int x2 = 0; x2 < 5; x2++) {
        if (!((m2 >> x2) & 1)) continue;
        f(x0 * 25 + x1 * 5 + x2);
      }
    }
  }
}

__global__ __launch_bounds__(64, 1) void hmm_scan_kernel(
    const int* __restrict__ inp, const float* __restrict__ w,
    const float* __restrict__ ek, const float* __restrict__ ik,
    float* __restrict__ out) {
  __shared__ __align__(16) float Bt_lds[NEMIT * S];  // Bt[col*S + state], 54.4 KB
  __shared__ __align__(8) float alpha_lds[128];      // pad: lanes 54..63 write junk slots
  __shared__ float pi_lds[S];
  __shared__ short arow[288], acol[288];
  __shared__ float avalS[288];
  __shared__ int s_ne, s_ncalls;
  __shared__ unsigned char cst[116], cs0[116], cs1[116], cs2[116], cxm[116], ctr[116];
  __shared__ int kOffL[116];

  const int tid = threadIdx.x;   // 64 threads = 1 wave

  // ---------- phase 0: zero Bt; serial builders on lanes 0/1/2 ----------
  for (int i = tid; i < NEMIT * S; i += 64) Bt_lds[i] = 0.f;

  if (tid == 0) {
    int c = 0;
    auto CC = [&](int st, int a, int b, int d, int xm, int tr) {
      cst[c] = (unsigned char)st; cs0[c] = (unsigned char)a; cs1[c] = (unsigned char)b;
      cs2[c] = (unsigned char)d; cxm[c] = (unsigned char)xm; ctr[c] = (unsigned char)tr; c++;
    };
    CC(0, 4, 4, 4, 0, 1);            // 'N'
    CC(1, 4, 4, 0, 0, 1);            // 'A'
    CC(2, 4, 0, 3, 0, 1);            // 'AT'
    CC(3, 0, 3, 2, 2, 0);            // 'ATG'  (non-trainable)
    CC(4, 3, 2, 4, 2, 1);            // 'ATGN'
    CC(5, 2, 4, 4, 2, 1);            // 'ATGNN'
    for (int s = 6; s <= 51; s++) CC(s, 4, 4, 4, 2, 1);
    CC(52, 4, 4, 3, 2, 1);           // 'T'
    CC(53, 4, 3, 0, 2, 1);           // 'TA'
    CC(53, 4, 3, 2, 2, 1);           // 'TG'
    CC(54, 3, 0, 0, 2, 0);           // 'TAA'
    CC(54, 3, 0, 2, 2, 0);           // 'TAG'
    CC(54, 3, 2, 0, 2, 0);           // 'TGA'
    CC(55, 4, 4, 4, 2, 1);
    for (int s = 56; s <= 106; s++) CC(s, 4, 4, 4, 2, 1);
    CC(107, 5, 5, 5, 2, 1);          // 'X' special (col 125, widx -1)
    s_ncalls = c;                    // = 111
  }
  if (tid == 1) {
    int ne = 0;
    auto AD = [&](int r, int c2, float v) {
      arow[ne] = (short)r; acol[ne] = (short)c2; avalS[ne] = v; ne++;
    };
    float w0 = w[0];
    AD(0, 0, 1.f - w0); AD(0, 1, w0); AD(1, 2, 1.f); AD(2, 3, 1.f);
    int k = 1;
    for (int i = 0; i < NCOD; i++) AD(3 + 3 * i, 4 + 3 * i, w[k + i]);
    k += NCOD;                                            // k = 17
    for (int i = 0; i < NCOD; i++) AD(4 + 3 * i, 5 + 3 * i, 1.f);
    for (int i = 0; i < NCOD; i++) AD(5 + 3 * i, 6 + 3 * i, 1.f);
    for (int i = 0; i <= NCOD; i++) AD(3 + 3 * i, 56 + 3 * i, w[k + i]);
    k += NCOD + 1;                                        // k = 34
    AD(51, 52, w[k]); k += 1;                             // k = 35
    for (int i = 0; i <= NCOD; i++) AD(56 + 3 * i, 57 + 3 * i, 1.f);
    for (int i = 0; i <= NCOD; i++) AD(57 + 3 * i, 58 + 3 * i, 1.f);
    for (int i = 0; i <= NCOD; i++) AD(58 + 3 * i, 4 + 3 * i, w[k + i]);
    for (int i = 0; i <= NCOD; i++) AD(58 + 3 * i, 56 + 3 * i, 1.f - w[k + i]);
    k += NCOD + 1;                                        // k = 52
    float wk = w[k];
    float sgnw = (wk > 0.f) ? 1.f : ((wk < 0.f) ? -1.f : 0.f);
    for (int a = 0; a < NCOD; a++)
      for (int jj = a + 1; jj <= NCOD; jj++) {
        int e = jj - a + 1;
        float sgn = (e & 1) ? sgnw : 1.f;
        AD(3 + 3 * a, 4 + 3 * jj, 1.f - sgn * powf(fabsf(wk), (float)e));
      }
    AD(52, 53, 1.f); AD(53, 54, 1.f); AD(54, 55, 1.f);
    AD(55, 55, 1.f); AD(55, 107, 1.f); AD(107, 107, 1.f);
    s_ne = ne;                                            // = 280
  }
  if (tid == 2) {
    float m = -1e30f;
    for (int i = 0; i < S; i++) m = fmaxf(m, ik[i]);
    float z = 0.f;
    for (int i = 0; i < S; i++) z += expf(ik[i] - m);
    for (int i = 0; i < S; i++) pi_lds[i] = expf(ik[i] - m) / z;
  }
  __syncthreads();

  const int ncalls = s_ncalls;
  const int ne = s_ne;

  // ---------- phase 1: per-call weight offsets; A row-softmax ----------
  for (int cc = tid; cc < ncalls; cc += 64) {
    int ko = 0;
    for (int c = 0; c < cc; c++) {
      if (ctr[c] && cs0[c] != 5) {
        int cnt = 0;
        enumCall(cs0[c], cs1[c], cs2[c], cxm[c], [&](int) { cnt++; });
        ko += cnt;
      }
    }
    kOffL[cc] = ko;
  }
  for (int s = tid; s < S; s += 64) {    // A row-softmax, in-place on avalS
    float m = -1e30f;
    for (int e = 0; e < ne; e++)
      if (arow[e] == s) m = fmaxf(m, avalS[e]);
    float z = 0.f;
    for (int e = 0; e < ne; e++)
      if (arow[e] == s) z += expf(avalS[e] - m);
    for (int e = 0; e < ne; e++)
      if (arow[e] == s) avalS[e] = expf(avalS[e] - m) / z;
  }
  __syncthreads();

  // ---------- phase 2: B row-softmax -> Bt_lds ----------
  for (int s = tid; s < S; s += 64) {
    float m = -1e30f;
    for (int c = 0; c < ncalls; c++) {
      if (cst[c] != s) continue;
      if (cs0[c] == 5) { m = fmaxf(m, 1.f); continue; }
      if (ctr[c]) {
        int ko = kOffL[c];
        enumCall(cs0[c], cs1[c], cs2[c], cxm[c], [&](int) { m = fmaxf(m, ek[ko++]); });
      } else {
        m = fmaxf(m, 1.f);
      }
    }
    float z = 0.f;
    for (int c = 0; c < ncalls; c++) {
      if (cst[c] != s) continue;
      if (cs0[c] == 5) { z += expf(1.f - m); continue; }
      if (ctr[c]) {
        int ko = kOffL[c];
        enumCall(cs0[c], cs1[c], cs2[c], cxm[c], [&](int) { z += expf(ek[ko++] - m); });
      } else {
        enumCall(cs0[c], cs1[c], cs2[c], cxm[c], [&](int) { z += expf(1.f - m); });
      }
    }
    for (int c = 0; c < ncalls; c++) {
      if (cst[c] != s) continue;
      if (cs0[c] == 5) { Bt_lds[125 * S + s] = expf(1.f - m) / z; continue; }
      if (ctr[c]) {
        int ko = kOffL[c];
        enumCall(cs0[c], cs1[c], cs2[c], cxm[c],
                 [&](int col) { Bt_lds[col * S + s] = expf(ek[ko++] - m) / z; });
      } else {
        enumCall(cs0[c], cs1[c], cs2[c], cxm[c],
                 [&](int col) { Bt_lds[col * S + s] = expf(1.f - m) / z; });
      }
    }
  }

  // ---------- phase 3: per-lane CSC of columns (2l, 2l+1), static slots ----------
  const int s0 = (tid < 54) ? 2 * tid : -1;
  const int s1 = (tid < 54) ? 2 * tid + 1 : -1;
  float gv0[MAXP], gv1[MAXP];
  int gi[MAXP];
#pragma unroll
  for (int e = 0; e < MAXP; e++) { gv0[e] = 0.f; gv1[e] = 0.f; gi[e] = 0; }
  {
    int cnt = 0;
    for (int e = 0; e < ne; e++) {
      const int c = (int)acol[e];
      if (c == s0 || c == s1) {
        const float v = avalS[e];
        const float v0 = (c == s0) ? v : 0.f;
        const float v1 = (c == s1) ? v : 0.f;
        const int r = (int)arow[e];
#pragma unroll
        for (int slot = 0; slot < MAXP; slot++)
          if (cnt == slot) { gi[slot] = r; gv0[slot] = v0; gv1[slot] = v1; }
        cnt++;
      }
    }
  }
  const float p0 = (tid < 54) ? pi_lds[2 * tid] : 0.f;
  const float p1 = (tid < 54) ? pi_lds[2 * tid + 1] : 0.f;
  __syncthreads();   // Bt_lds + avalS consumption done

  // ---------- phase 4: un-normalized forward scan (no per-step reduce) ----------
  const int* seq = inp + (size_t)blockIdx.x * T_LEN;
  float* ob = out + (size_t)blockIdx.x * T_LEN * S;
  const int l2 = 2 * tid;

  int e0 = seq[0];
  float u0 = 0.f, u1 = 0.f;
  if (tid < 54) {
    u0 = p0 * Bt_lds[e0 * S + l2];
    u1 = p1 * Bt_lds[e0 * S + l2 + 1];
    *(float2*)&ob[l2] = make_float2(u0, u1);
  }
  *(float2*)&alpha_lds[l2] = make_float2(u0, u1);   // lanes>=54 write pad slots (0)
  __syncthreads();

  int etn = seq[1];
  for (int t = 1; t < T_LEN; t++) {
    const int ecur = etn;
    if (t + 1 < T_LEN) etn = seq[t + 1];   // uniform prefetch of next symbol
    float a0 = 0.f, a1 = 0.f, b0 = 0.f, b1 = 0.f;
#pragma unroll
    for (int e = 0; e < MAXP; e += 2) {
      const float x = alpha_lds[gi[e]];
      const float y = alpha_lds[gi[e + 1]];
      a0 += x * gv0[e];     b0 += x * gv1[e];
      a1 += y * gv0[e + 1]; b1 += y * gv1[e + 1];
    }
    const float2 bt = *(const float2*)&Bt_lds[ecur * S + l2];
    u0 = (a0 + a1) * bt.x;
    u1 = (b0 + b1) * bt.y;

    if ((t & 15) == 15) {                  // periodic rescale, off critical path ratio
      float m = fmaxf(u0, u1);
#pragma unroll
      for (int msk = 1; msk < 64; msk <<= 1) m = fmaxf(m, __shfl_xor(m, msk, 64));
      const float r = 1.f / m;
      u0 *= r; u1 *= r;
    }

    *(float2*)&alpha_lds[l2] = make_float2(u0, u1);
    if (tid < 54) *(float2*)&ob[(size_t)t * S + l2] = make_float2(u0, u1);
    __syncthreads();   // single wave: lgkmcnt fence so next-step gathers see writes
  }
}

// ---------- kernel 2: per-row normalization, fully parallel, BW-bound ----------
__global__ __launch_bounds__(256, 8) void hmm_norm_kernel(float* __restrict__ out,
                                                          int nrows) {
  const int wid = (int)((blockIdx.x * 256u + threadIdx.x) >> 6);  // one wave per row
  const int l = threadIdx.x & 63;
  if (wid >= nrows) return;
  float* row = out + (size_t)wid * S;
  float2 x = make_float2(0.f, 0.f);
  if (l < 54) x = *(const float2*)&row[2 * l];
  float s = x.x + x.y;
#pragma unroll
  for (int msk = 1; msk < 64; msk <<= 1) s += __shfl_xor(s, msk, 64);
  const float inv = 1.f / s;
  if (l < 54) *(float2*)&row[2 * l] = make_float2(x.x * inv, x.y * inv);
}

extern "C" void kernel_launch(void* const* d_in, const int* in_sizes, int n_in,
                              void* d_out, int out_size, void* d_ws, size_t ws_size,
                              hipStream_t stream) {
  const int* inp = (const int*)d_in[0];        // [256, 2048] int32 kmer ids
  const float* w = (const float*)d_in[1];      // transition_kernel [53]
  const float* ek = (const float*)d_in[2];     // emission_kernel [108*216]
  const float* ik = (const float*)d_in[3];     // init_kernel [108]
  float* out = (float*)d_out;                  // [256, 2048, 108] f32
  (void)d_ws; (void)ws_size; (void)in_sizes; (void)n_in; (void)out_size;
  hmm_scan_kernel<<<N_BATCH, 64, 0, stream>>>(inp, w, ek, ik, out);
  const int nrows = N_BATCH * T_LEN;           // 524288 rows
  hmm_norm_kernel<<<nrows / 4, 256, 0, stream>>>(out, nrows);
}